// Round 2
// baseline (79.991 us; speedup 1.0000x reference)
//
#include <hip/hip_runtime.h>

#define LATENT 16
#define STATE  16
#define LIB    169            // 1 + 16 + 136 + 16
#define NPOS   (64 * 8192)    // BATCH * T

// ---- prep: W[l,d] = mask[l,d] * coef[l,d] (2704 floats into d_ws) ----
__global__ __launch_bounds__(256) void prep_w(const float* __restrict__ coef,
                                              const float* __restrict__ mask,
                                              float* __restrict__ W) {
    int i = blockIdx.x * blockDim.x + threadIdx.x;
    if (i < LIB * STATE) W[i] = coef[i] * mask[i];
}

// ---- main: each thread computes 2 positions (R=2), fully unrolled ----
__global__ __launch_bounds__(256) void sindy_main(const float* __restrict__ x,
                                                  const float* __restrict__ W,
                                                  float* __restrict__ out) {
    const int tid = threadIdx.x;
    const long p0 = (long)blockIdx.x * 512 + tid;  // position 0
    const long p1 = p0 + 256;                      // position 1 (stride keeps coalescing)

    // Load x for both positions: 4 x float4 each, coalesced 16B/lane.
    float xs0[LATENT], xs1[LATENT];
    {
        const float4* xv = (const float4*)x;
        #pragma unroll
        for (int q = 0; q < 4; ++q) {
            float4 a = xv[p0 * 4 + q];
            xs0[q * 4 + 0] = a.x; xs0[q * 4 + 1] = a.y;
            xs0[q * 4 + 2] = a.z; xs0[q * 4 + 3] = a.w;
            float4 b = xv[p1 * 4 + q];
            xs1[q * 4 + 0] = b.x; xs1[q * 4 + 1] = b.y;
            xs1[q * 4 + 2] = b.z; xs1[q * 4 + 3] = b.w;
        }
    }

    const float4* W4 = (const float4*)W;   // W row l = W4[l*4 .. l*4+3]

    // Accumulators init with constant term (theta_0 == 1): acc = W[0,:]
    float4 acc0[4], acc1[4];
    #pragma unroll
    for (int q = 0; q < 4; ++q) {
        float4 w = W4[q];
        acc0[q] = w;
        acc1[q] = w;
    }

    // FMA one library row l with per-position features f0, f1.
    // l is wave-uniform and compile-time after unroll -> s_load of W expected.
    auto term = [&](int l, float f0, float f1) {
        #pragma unroll
        for (int q = 0; q < 4; ++q) {
            float4 w = W4[l * 4 + q];
            acc0[q].x = fmaf(f0, w.x, acc0[q].x);
            acc0[q].y = fmaf(f0, w.y, acc0[q].y);
            acc0[q].z = fmaf(f0, w.z, acc0[q].z);
            acc0[q].w = fmaf(f0, w.w, acc0[q].w);
            acc1[q].x = fmaf(f1, w.x, acc1[q].x);
            acc1[q].y = fmaf(f1, w.y, acc1[q].y);
            acc1[q].z = fmaf(f1, w.z, acc1[q].z);
            acc1[q].w = fmaf(f1, w.w, acc1[q].w);
        }
    };

    // Linear terms: l = 1..16
    #pragma unroll
    for (int i = 0; i < LATENT; ++i) term(1 + i, xs0[i], xs1[i]);

    // Quadratic terms: l = 17..152, order (i,j) i<=j matching
    // itertools.combinations_with_replacement(range(16), 2)
    {
        int l = 17;
        #pragma unroll
        for (int i = 0; i < LATENT; ++i) {
            #pragma unroll
            for (int j = i; j < LATENT; ++j) {
                term(l, xs0[i] * xs0[j], xs1[i] * xs1[j]);
                ++l;
            }
        }
    }

    // Sin terms: l = 153..168
    #pragma unroll
    for (int i = 0; i < LATENT; ++i) term(153 + i, __sinf(xs0[i]), __sinf(xs1[i]));

    // Store: 4 x float4 per position, coalesced.
    float4* o = (float4*)out;
    #pragma unroll
    for (int q = 0; q < 4; ++q) {
        o[p0 * 4 + q] = acc0[q];
        o[p1 * 4 + q] = acc1[q];
    }
}

extern "C" void kernel_launch(void* const* d_in, const int* in_sizes, int n_in,
                              void* d_out, int out_size, void* d_ws, size_t ws_size,
                              hipStream_t stream) {
    const float* x    = (const float*)d_in[0];
    const float* coef = (const float*)d_in[1];
    const float* mask = (const float*)d_in[2];
    float*       W    = (float*)d_ws;         // 2704 floats scratch
    float*       out  = (float*)d_out;

    prep_w<<<(LIB * STATE + 255) / 256, 256, 0, stream>>>(coef, mask, W);
    sindy_main<<<NPOS / 512, 256, 0, stream>>>(x, W, out);
}

// Round 3
// 25.439 us; speedup vs baseline: 3.1444x; 3.1444x over previous
//
#include <hip/hip_runtime.h>
#include <hip/hip_bf16.h>

#define LATENT 16
#define STATE  16
#define NPOS   (64 * 8192)
#define NTILES (NPOS / 16)        // 32768 tiles of 16 positions
#define NCHUNK 9                  // K = 288 = 9 * 32

typedef __attribute__((ext_vector_type(4))) float f32x4;
typedef __attribute__((ext_vector_type(8))) short bf16x8;  // 8 bf16 in 4 VGPRs

static __device__ __forceinline__ short f2bf(float f) {
    __hip_bfloat16 h = __float2bfloat16(f);
    return (short)__builtin_bit_cast(unsigned short, h);
}

// ---------------- prep: pack W into MFMA B-fragment order ----------------
// ws layout: [0..15] f32 bias (const-term row); then 4608 ushort Wpack.
// Wpack[(c*64 + lane)*8 + jj] = bf16 W'[k = c*32 + (lane>>4)*8 + jj][col = lane&15]
// New K order: k<256: x_I * x_J, I=k>>4, J=k&15 (off-diag weights halved);
//              k=256..271: linear x[k-256]; k=272..287: sin(x[k-272]).
__global__ __launch_bounds__(256) void prep_pack(const float* __restrict__ coef,
                                                 const float* __restrict__ mask,
                                                 float* __restrict__ wsf) {
    int id = blockIdx.x * 256 + threadIdx.x;
    if (id < 16) wsf[id] = coef[id] * mask[id];   // bias: ref row 0 (const)
    if (id >= 4608) return;
    int jj  = id & 7;
    int col = (id >> 3) & 15;
    int g   = (id >> 7) & 3;
    int c   = id >> 9;                    // 0..8
    int k   = c * 32 + g * 8 + jj;        // 0..287
    float scale = 1.0f;
    int row;
    if (k < 256) {
        int I = k >> 4, J = k & 15;
        int im = I < J ? I : J, jm = I < J ? J : I;
        int q = im * 16 - im * (im - 1) / 2 + (jm - im);  // combinations_with_replacement index
        row = 17 + q;
        if (I != J) scale = 0.5f;
    } else if (k < 272) {
        row = 1 + (k - 256);
    } else {
        row = 153 + (k - 272);
    }
    float w = coef[row * STATE + col] * mask[row * STATE + col] * scale;
    ((ushort*)(wsf + 16))[id] = (ushort)f2bf(w);
}

// ---------------- main: theta-on-the-fly MFMA GEMM ----------------
// One wave per 16-position tile-stream, 4 tiles/wave, no __syncthreads
// (each wave owns its LDS region; LDS row stride 20 floats kills conflicts).
__global__ __launch_bounds__(256) void sindy_mfma(const float* __restrict__ x,
                                                  const float* __restrict__ wsf,
                                                  float* __restrict__ out) {
    const int lane  = threadIdx.x & 63;
    const int wid   = threadIdx.x >> 6;
    const int g     = lane >> 4;          // K-slice group 0..3
    const int col   = lane & 15;          // A-row (position in tile) and D-col
    const int j0    = (g & 1) * 8;        // J-half this lane multiplies
    const int ihalf = g >> 1;             // I parity this lane covers

    // B fragments: wave-wide resident, loaded once (9 x 16B per lane)
    const ushort* Wpack = (const ushort*)(wsf + 16);
    bf16x8 bfrag[NCHUNK];
    #pragma unroll
    for (int c = 0; c < NCHUNK; ++c)
        bfrag[c] = *(const bf16x8*)(Wpack + (c * 64 + lane) * 8);

    const float bias = wsf[col];

    __shared__ float lds[4][2][16 * 20];  // [wave][dbuf][pos*20]
    const float4* x4 = (const float4*)x;

    const int wave_gid = blockIdx.x * 4 + wid;   // 8192 waves
    const int tile0 = wave_gid * 4;

    float4 nxt = x4[(long)tile0 * 64 + lane];
    #pragma unroll
    for (int t = 0; t < 4; ++t) {
        const int tile = tile0 + t;
        float* myl = lds[wid][t & 1];
        // stage 16 pos x 16 floats, coalesced load done, padded-stride write
        *(float4*)&myl[(lane >> 2) * 20 + (lane & 3) * 4] = nxt;
        if (t < 3) nxt = x4[(long)(tile + 1) * 64 + lane];  // prefetch next tile

        // per-lane operands for its A K-slice
        float xv[8];
        *(float4*)&xv[0] = *(const float4*)&myl[col * 20 + j0];
        *(float4*)&xv[4] = *(const float4*)&myl[col * 20 + j0 + 4];
        float xi[8];
        #pragma unroll
        for (int c = 0; c < 8; ++c) xi[c] = myl[col * 20 + ihalf + 2 * c];

        f32x4 acc = {bias, bias, bias, bias};

        // quad chunks: A[col][c*32+g*8+jj] = x[2c+ihalf] * x[j0+jj]
        #pragma unroll
        for (int c = 0; c < 8; ++c) {
            bf16x8 a;
            #pragma unroll
            for (int j = 0; j < 8; ++j) a[j] = f2bf(xi[c] * xv[j]);
            acc = __builtin_amdgcn_mfma_f32_16x16x32_bf16(a, bfrag[c], acc, 0, 0, 0);
        }
        // chunk 8: g<2 -> linear x[j0+jj]; g>=2 -> sin(x[j0+jj])
        {
            const bool us = (g >= 2);
            bf16x8 a;
            #pragma unroll
            for (int j = 0; j < 8; ++j) {
                float f = us ? __sinf(xv[j]) : xv[j];
                a[j] = f2bf(f);
            }
            acc = __builtin_amdgcn_mfma_f32_16x16x32_bf16(a, bfrag[8], acc, 0, 0, 0);
        }

        // D: row = g*4 + r (position), col = state; 64B-line coalesced
        #pragma unroll
        for (int r = 0; r < 4; ++r)
            out[(long)(tile * 16 + g * 4 + r) * STATE + col] = acc[r];
    }
}

extern "C" void kernel_launch(void* const* d_in, const int* in_sizes, int n_in,
                              void* d_out, int out_size, void* d_ws, size_t ws_size,
                              hipStream_t stream) {
    const float* x    = (const float*)d_in[0];
    const float* coef = (const float*)d_in[1];
    const float* mask = (const float*)d_in[2];
    float*       wsf  = (float*)d_ws;     // 16 f32 bias + 4608 ushort Wpack
    float*       out  = (float*)d_out;

    prep_pack<<<18, 256, 0, stream>>>(coef, mask, wsf);
    sindy_mfma<<<NTILES / 16, 256, 0, stream>>>(x, wsf, out);  // 2048 blocks, 4 waves, 4 tiles/wave
}